// Round 8
// baseline (542.577 us; speedup 1.0000x reference)
//
#include <hip/hip_runtime.h>

// ---------------------------------------------------------------------------
// ExtraPositionPromptSABottleneck on MI355X (gfx950)
// B=8, DIMS=512, C=256, H=W=64, N=4096.
//
// Round 12:
//  - gemm_core_256 rewritten as a phase-split schedule (T3+T4, m201
//    template): 4 phases per K-tile, each {ds_read one quadrant -> setprio
//    -> 16 MFMA -> setprio -> barrier}; next tile's A-loads issued at
//    phase 0, B-loads at phase 1; ONE counted s_waitcnt vmcnt(4) per K-tile
//    (vmcnt(0) only on the last).  r11 showed all pipes <25% busy at the
//    2-phase schedule; per the regime-gate, 8-phase is the prerequisite
//    for T2/T5 to pay.
//  - r11's LDS-staged store epilogues REVERTED (measured -7%: WRITE_SIZE
//    was already ideal 132MB -> scattered 2B stores were never the issue).
// ---------------------------------------------------------------------------

typedef __bf16 bf16;
typedef __attribute__((ext_vector_type(8))) __bf16 bf16x8;
typedef __attribute__((ext_vector_type(4))) __bf16 bf16x4;
typedef __attribute__((ext_vector_type(2))) __bf16 bf16x2;
typedef __attribute__((ext_vector_type(4))) float f32x4;

__device__ __forceinline__ float silu_f(float x) { return x / (1.f + __expf(-x)); }

__device__ __forceinline__ void zero_acc(f32x4 (&acc)[4][4])
{
#pragma unroll
    for (int i = 0; i < 4; ++i)
#pragma unroll
        for (int j = 0; j < 4; ++j)
            acc[i][j] = (f32x4){0.f, 0.f, 0.f, 0.f};
}

__device__ __forceinline__ void load_lds16(const bf16* g, bf16* l)
{
    __builtin_amdgcn_global_load_lds(
        (const __attribute__((address_space(1))) unsigned int*)g,
        (__attribute__((address_space(3))) unsigned int*)l, 16, 0, 0);
}

__device__ __forceinline__ void wg_barrier()
{
    asm volatile("" ::: "memory");
    __builtin_amdgcn_s_barrier();
    asm volatile("" ::: "memory");
}

// ---- counted-vmcnt double-buffered GEMM core: 256 thr, tile 128x128, BK=32
// (used by gemm1, rhw)
__device__ __forceinline__ void gemm_core_db(
    const bf16* __restrict__ A, int lda,
    const bf16* __restrict__ B, int ldb,
    int K, f32x4 (&acc)[4][4])
{
    __shared__ bf16 As[2][128 * 32];
    __shared__ bf16 Bs[2][128 * 32];
    const int tid = threadIdx.x;
    const int wave = tid >> 6;
    const int lane = tid & 63;
    const int lm = lane & 15;
    const int kq = lane >> 4;
    const int m0 = (wave >> 1) * 64;
    const int n0 = (wave & 1) * 64;
    const int srow = tid >> 2;
    const int skoff = (((tid & 3) ^ ((tid >> 3) & 3))) * 8;
    const int krd = (kq ^ ((lm >> 1) & 3)) * 8;
    zero_acc(acc);
    const bf16* ga = A + (size_t)srow * lda + skoff;
    const bf16* gb = B + (size_t)srow * ldb + skoff;
    load_lds16(ga, As[0] + tid * 8);
    load_lds16(ga + (size_t)64 * lda, As[0] + tid * 8 + 64 * 32);
    load_lds16(gb, Bs[0] + tid * 8);
    load_lds16(gb + (size_t)64 * ldb, Bs[0] + tid * 8 + 64 * 32);
    const int nt = K >> 5;
    for (int t = 0; t < nt; ++t) {
        const int cur = t & 1;
        if (t + 1 < nt) {
            const bf16* na = ga + (t + 1) * 32;
            const bf16* nb = gb + (t + 1) * 32;
            bf16* dA = As[cur ^ 1] + tid * 8;
            bf16* dB = Bs[cur ^ 1] + tid * 8;
            load_lds16(na, dA);
            load_lds16(na + (size_t)64 * lda, dA + 64 * 32);
            load_lds16(nb, dB);
            load_lds16(nb + (size_t)64 * ldb, dB + 64 * 32);
            asm volatile("s_waitcnt vmcnt(4)" ::: "memory");
        } else {
            asm volatile("s_waitcnt vmcnt(0)" ::: "memory");
        }
        wg_barrier();
        const bf16* as = As[cur];
        const bf16* bs = Bs[cur];
        bf16x8 av[4], bv[4];
#pragma unroll
        for (int tt = 0; tt < 4; ++tt)
            av[tt] = *(const bf16x8*)(as + (m0 + tt * 16 + lm) * 32 + krd);
#pragma unroll
        for (int tt = 0; tt < 4; ++tt)
            bv[tt] = *(const bf16x8*)(bs + (n0 + tt * 16 + lm) * 32 + krd);
#pragma unroll
        for (int i = 0; i < 4; ++i)
#pragma unroll
            for (int j = 0; j < 4; ++j)
                acc[i][j] = __builtin_amdgcn_mfma_f32_16x16x32_bf16(
                    av[i], bv[j], acc[i][j], 0, 0, 0);
        wg_barrier();
    }
}

// ---- 256x256 / BK=64 / 512-thread (8-wave, 2m x 4n) GEMM core,
// phase-split schedule: 4 phases per K-tile (= m201's 8 phases / 2 tiles).
// As/Bs: caller-provided LDS, 2*16384 bf16 each (double-buffered).
__device__ __forceinline__ void gemm_core_256(
    const bf16* __restrict__ A, int lda,
    const bf16* __restrict__ B, int ldb,
    int K, f32x4 (&acc)[8][4], bf16* As, bf16* Bs)
{
    const int tid = threadIdx.x;
    const int lane = tid & 63;
    const int wid = tid >> 6;
    const int wm = wid >> 2, wn = wid & 3;
    const int lm = lane & 15, kq = lane >> 4;
    const int srow = tid >> 3;
    const int skoff = ((tid & 7) ^ (srow & 7)) * 8;
    const int arow = wm * 128 + lm;
    const int brow = wn * 64 + lm;
    const bf16* ga = A + (size_t)srow * lda + skoff;
    const bf16* gb = B + (size_t)srow * ldb + skoff;
    // prologue: stage tile 0 into buffer 0 (8 loads/thread)
#pragma unroll
    for (int r = 0; r < 4; ++r)
        load_lds16(ga + (size_t)(64 * r) * lda, As + tid * 8 + r * 4096);
#pragma unroll
    for (int r = 0; r < 4; ++r)
        load_lds16(gb + (size_t)(64 * r) * ldb, Bs + tid * 8 + r * 4096);
#pragma unroll
    for (int i = 0; i < 8; ++i)
#pragma unroll
        for (int j = 0; j < 4; ++j)
            acc[i][j] = (f32x4){0.f, 0.f, 0.f, 0.f};
    const int nt = K >> 6;
    for (int t = 0; t < nt; ++t) {
        const int cur = t & 1;
        const bf16* as = As + cur * 16384;
        const bf16* bs = Bs + cur * 16384;
        bf16* dA = As + (cur ^ 1) * 16384;
        bf16* dB = Bs + (cur ^ 1) * 16384;
        const bf16* na = ga + (size_t)(t + 1) * 64;
        const bf16* nb = gb + (size_t)(t + 1) * 64;
        const bool pf = (t + 1 < nt);
        bf16x8 av[4], bv[4];
        // ---- phase 0: issue A(t+1); gate tile t; ks=0, i=0..3
        // (prefetch writes buf[cur^1], last read in tile t-1; t-1's final
        //  barrier orders those reads before this issue)
        if (pf) {
#pragma unroll
            for (int r = 0; r < 4; ++r)
                load_lds16(na + (size_t)(64 * r) * lda, dA + tid * 8 + r * 4096);
            asm volatile("s_waitcnt vmcnt(4)" ::: "memory");
        } else {
            asm volatile("s_waitcnt vmcnt(0)" ::: "memory");
        }
        wg_barrier();
#pragma unroll
        for (int j = 0; j < 4; ++j) {
            int lr = brow + j * 16;
            bv[j] = *(const bf16x8*)(bs + lr * 64 + (kq ^ (lr & 7)) * 8);
        }
#pragma unroll
        for (int i = 0; i < 4; ++i) {
            int lr = arow + i * 16;
            av[i] = *(const bf16x8*)(as + lr * 64 + (kq ^ (lr & 7)) * 8);
        }
        __builtin_amdgcn_s_setprio(1);
#pragma unroll
        for (int i = 0; i < 4; ++i)
#pragma unroll
            for (int j = 0; j < 4; ++j)
                acc[i][j] = __builtin_amdgcn_mfma_f32_16x16x32_bf16(
                    av[i], bv[j], acc[i][j], 0, 0, 0);
        __builtin_amdgcn_s_setprio(0);
        wg_barrier();
        // ---- phase 1: issue B(t+1); ks=0, i=4..7 (bv kept)
        if (pf) {
#pragma unroll
            for (int r = 0; r < 4; ++r)
                load_lds16(nb + (size_t)(64 * r) * ldb, dB + tid * 8 + r * 4096);
        }
#pragma unroll
        for (int i = 0; i < 4; ++i) {
            int lr = arow + (i + 4) * 16;
            av[i] = *(const bf16x8*)(as + lr * 64 + (kq ^ (lr & 7)) * 8);
        }
        __builtin_amdgcn_s_setprio(1);
#pragma unroll
        for (int i = 0; i < 4; ++i)
#pragma unroll
            for (int j = 0; j < 4; ++j)
                acc[i + 4][j] = __builtin_amdgcn_mfma_f32_16x16x32_bf16(
                    av[i], bv[j], acc[i + 4][j], 0, 0, 0);
        __builtin_amdgcn_s_setprio(0);
        wg_barrier();
        // ---- phase 2: ks=1, i=0..3 (reload bv)
#pragma unroll
        for (int j = 0; j < 4; ++j) {
            int lr = brow + j * 16;
            bv[j] = *(const bf16x8*)(bs + lr * 64 + ((4 | kq) ^ (lr & 7)) * 8);
        }
#pragma unroll
        for (int i = 0; i < 4; ++i) {
            int lr = arow + i * 16;
            av[i] = *(const bf16x8*)(as + lr * 64 + ((4 | kq) ^ (lr & 7)) * 8);
        }
        __builtin_amdgcn_s_setprio(1);
#pragma unroll
        for (int i = 0; i < 4; ++i)
#pragma unroll
            for (int j = 0; j < 4; ++j)
                acc[i][j] = __builtin_amdgcn_mfma_f32_16x16x32_bf16(
                    av[i], bv[j], acc[i][j], 0, 0, 0);
        __builtin_amdgcn_s_setprio(0);
        wg_barrier();
        // ---- phase 3: ks=1, i=4..7
#pragma unroll
        for (int i = 0; i < 4; ++i) {
            int lr = arow + (i + 4) * 16;
            av[i] = *(const bf16x8*)(as + lr * 64 + ((4 | kq) ^ (lr & 7)) * 8);
        }
        __builtin_amdgcn_s_setprio(1);
#pragma unroll
        for (int i = 0; i < 4; ++i)
#pragma unroll
            for (int j = 0; j < 4; ++j)
                acc[i + 4][j] = __builtin_amdgcn_mfma_f32_16x16x32_bf16(
                    av[i], bv[j], acc[i + 4][j], 0, 0, 0);
        __builtin_amdgcn_s_setprio(0);
        wg_barrier();   // final barrier: protects next tile's prefetch
    }
}

// ------------------------------ prep kernels -------------------------------

__global__ __launch_bounds__(256) void prep_misc_kernel(
    const float* __restrict__ cv1_w,
    const float* __restrict__ qw, const float* __restrict__ qb,
    const float* __restrict__ kw, const float* __restrict__ kb,
    const float* __restrict__ vw, const float* __restrict__ vb,
    const float* __restrict__ ew, const float* __restrict__ eb,
    const float* __restrict__ cv2_w,
    const float* __restrict__ g1, const float* __restrict__ b1,
    const float* __restrict__ m1, const float* __restrict__ v1,
    const float* __restrict__ g2, const float* __restrict__ b2,
    const float* __restrict__ m2, const float* __restrict__ v2,
    const float* __restrict__ rel_h, const float* __restrict__ rel_w,
    bf16* __restrict__ w1b, bf16* __restrict__ wqkve, bf16* __restrict__ w2b,
    bf16* __restrict__ posT,
    float* __restrict__ biasq,
    float* __restrict__ bn1s, float* __restrict__ bn1h,
    float* __restrict__ bn2s, float* __restrict__ bn2h)
{
    int idx = blockIdx.x * 256 + threadIdx.x;
    if (idx < 131072) { w1b[idx] = (bf16)cv1_w[idx]; return; }
    idx -= 131072;
    if (idx < 262144) {
        int j = idx >> 8, c = idx & 255;
        int p = j >> 8, r = j & 255;
        const float* w = (p == 0) ? qw : (p == 1) ? kw : (p == 2) ? vw : ew;
        wqkve[idx] = (bf16)w[r * 256 + c];
        return;
    }
    idx -= 262144;
    if (idx < 131072) { w2b[idx] = (bf16)cv2_w[idx]; return; }
    idx -= 131072;
    if (idx < 1024) {
        int p = idx >> 8, r = idx & 255;
        const float* bb = (p == 0) ? qb : (p == 1) ? kb : (p == 2) ? vb : eb;
        biasq[idx] = bb[r];
        return;
    }
    idx -= 1024;
    if (idx < 256) {
        float s = g1[idx] * rsqrtf(v1[idx] + 1e-5f);
        bn1s[idx] = s;
        bn1h[idx] = b1[idx] - m1[idx] * s;
        return;
    }
    idx -= 256;
    if (idx < 512) {
        float s = g2[idx] * rsqrtf(v2[idx] + 1e-5f);
        bn2s[idx] = s;
        bn2h[idx] = b2[idx] - m2[idx] * s;
        return;
    }
    idx -= 512;
    if (idx < 32768) {
        int r = idx >> 8, c = idx & 255;
        posT[idx] = (bf16)((r < 64) ? rel_h[c * 64 + r] : rel_w[c * 64 + (r - 64)]);
        return;
    }
}

__global__ __launch_bounds__(256) void zero_lsum_kernel(float* __restrict__ p)
{
    p[blockIdx.x * 256 + threadIdx.x] = 0.f;
}

// xt[b*4096+n][d] = (bf16) x[b][d][n]
__global__ __launch_bounds__(256) void transpose_x_kernel(
    const float* __restrict__ x, bf16* __restrict__ xt)
{
    __shared__ float tile[64][65];
    int b = blockIdx.z;
    int n0 = blockIdx.x * 64;
    int d0 = blockIdx.y * 64;
    int tx = threadIdx.x & 63, ty = threadIdx.x >> 6;
#pragma unroll
    for (int i = 0; i < 16; ++i) {
        int d = i * 4 + ty;
        tile[d][tx] = x[((size_t)(b * 512 + d0 + d)) * 4096 + n0 + tx];
    }
    __syncthreads();
#pragma unroll
    for (int i = 0; i < 16; ++i) {
        int n = i * 4 + ty;
        xt[((size_t)(b * 4096 + n0 + n)) * 512 + d0 + tx] = (bf16)tile[tx][n];
    }
}

// v_cm[b][c][m] = v_nm[b*4096+m][c]
__global__ __launch_bounds__(256) void transpose_v_kernel(
    const bf16* __restrict__ v_nm, bf16* __restrict__ v_cm)
{
    __shared__ float tile[64][65];
    int b = blockIdx.z;
    int m0 = blockIdx.x * 64;
    int c0 = blockIdx.y * 64;
    int tx = threadIdx.x & 63, ty = threadIdx.x >> 6;
#pragma unroll
    for (int i = 0; i < 16; ++i) {
        int m = i * 4 + ty;
        tile[m][tx] = (float)v_nm[((size_t)(b * 4096 + m0 + m)) * 256 + c0 + tx];
    }
    __syncthreads();
#pragma unroll
    for (int i = 0; i < 16; ++i) {
        int c = i * 4 + ty;
        v_cm[((size_t)(b * 256 + c0 + c)) * 4096 + m0 + tx] = (bf16)tile[tx][c];
    }
}

// ------------------------------ GEMM kernels -------------------------------

__global__ __launch_bounds__(256) void gemm1_kernel(
    const bf16* __restrict__ xt, const bf16* __restrict__ w1b,
    const float* __restrict__ bn1s, const float* __restrict__ bn1h,
    bf16* __restrict__ x1t)
{
    const bf16* A = xt + (size_t)(blockIdx.y * 128) * 512;
    const bf16* Bm = w1b + (size_t)(blockIdx.x * 128) * 512;
    f32x4 acc[4][4];
    gemm_core_db(A, 512, Bm, 512, 512, acc);
    int wave = threadIdx.x >> 6;
    int lane = threadIdx.x & 63;
    int m0 = blockIdx.y * 128 + (wave >> 1) * 64;
    int n0 = blockIdx.x * 128 + (wave & 1) * 64;
    int lm = lane & 15, kq = lane >> 4;
#pragma unroll
    for (int i = 0; i < 4; ++i)
#pragma unroll
        for (int j = 0; j < 4; ++j)
#pragma unroll
            for (int r = 0; r < 4; ++r) {
                int row = m0 + i * 16 + kq * 4 + r;
                int col = n0 + j * 16 + lm;
                float h = bn1s[col] * acc[i][j][r] + bn1h[col];
                x1t[(size_t)row * 256 + col] = (bf16)silu_f(h);
            }
}

// projections on the 256^2 core: bx=0,1 -> qk; bx=2 -> v_nm; bx=3 -> e_nm
__global__ __launch_bounds__(512, 1) void gemm2_kernel(
    const bf16* __restrict__ x1t, const bf16* __restrict__ wqkve,
    const float* __restrict__ biasq,
    bf16* __restrict__ qk, bf16* __restrict__ v_nm, bf16* __restrict__ e_nm)
{
    __shared__ bf16 smem[65536];
    const int bx = blockIdx.x, by = blockIdx.y;
    const bf16* A = x1t + (size_t)(by * 256) * 256;
    const bf16* Bm = wqkve + (size_t)(bx * 256) * 256;
    f32x4 acc[8][4];
    gemm_core_256(A, 256, Bm, 256, 256, acc, smem, smem + 32768);
    const int tid = threadIdx.x, lane = tid & 63, wid = tid >> 6;
    const int wm = wid >> 2, wn = wid & 3, lm = lane & 15, kq = lane >> 4;
#pragma unroll
    for (int i = 0; i < 8; ++i)
#pragma unroll
        for (int j = 0; j < 4; ++j)
#pragma unroll
            for (int r = 0; r < 4; ++r) {
                int row = by * 256 + wm * 128 + i * 16 + kq * 4 + r;
                int col = bx * 256 + wn * 64 + j * 16 + lm;
                bf16 val = (bf16)(acc[i][j][r] + biasq[col]);
                if (bx < 2)          qk[(size_t)row * 512 + col] = val;
                else if (bx == 2)    v_nm[(size_t)row * 256 + (col - 512)] = val;
                else                 e_nm[(size_t)row * 256 + (col - 768)] = val;
            }
}

// rhwT[b][m][r] = sum_c posT[r][c] * e_nm[b*4096+m][c]  (r<64: RH, r>=64: RW)
__global__ __launch_bounds__(256) void gemm_rhw_kernel(
    const bf16* __restrict__ posT, const bf16* __restrict__ e_nm,
    bf16* __restrict__ rhwT)
{
    int b = blockIdx.z;
    const bf16* A = e_nm + ((size_t)b * 4096 + blockIdx.x * 128) * 256;
    f32x4 acc[4][4];
    gemm_core_db(A, 256, posT, 256, 256, acc);
    int wave = threadIdx.x >> 6;
    int lane = threadIdx.x & 63;
    int m0 = (wave >> 1) * 64, n0 = (wave & 1) * 64;
    int lm = lane & 15, kq = lane >> 4;
    bf16* rb = rhwT + ((size_t)b * 4096 + blockIdx.x * 128) * 128;
#pragma unroll
    for (int i = 0; i < 4; ++i)
#pragma unroll
        for (int j = 0; j < 4; ++j)
#pragma unroll
            for (int r = 0; r < 4; ++r)
                rb[(size_t)(m0 + i * 16 + kq * 4 + r) * 128 + n0 + j * 16 + lm] =
                    (bf16)acc[i][j][r];
}

// P[bz][n][m] = exp(q.k + RH + RW - 8), bf16; row sums -> lsum[bz][n]
__global__ __launch_bounds__(512, 1) void gemm3b_kernel(
    const bf16* __restrict__ qk, const bf16* __restrict__ rhwT,
    bf16* __restrict__ P, float* __restrict__ lsum, int gbase)
{
    __shared__ bf16 smem[65536];
    __shared__ float rs[256];
    // XCD-aware bijective swizzle (1024 blocks % 8 == 0)
    int flat = blockIdx.x + 16 * blockIdx.y + 256 * blockIdx.z;
    flat = (flat & 7) * 128 + (flat >> 3);
    const int bx = flat & 15, by = (flat >> 4) & 15, bz = flat >> 8;
    const int b = gbase + bz;
    const int tid = threadIdx.x;
    const int wid = tid >> 6;
    const int lane = tid & 63;
    const int wm = wid >> 2, wn = wid & 3;
    const int lm = lane & 15, kq = lane >> 4;
    const bf16* A = qk + ((size_t)b * 4096 + by * 256) * 512;        // q rows
    const bf16* Bm = qk + ((size_t)b * 4096 + bx * 256) * 512 + 256; // k rows
    f32x4 acc[8][4];
    gemm_core_256(A, 512, Bm, 512, 256, acc, smem, smem + 32768);
    // ---- positional terms
    bf16x2 rhv2[4];
    bf16x4 rwv[4][4];
    {
        const bf16* rbT = rhwT + ((size_t)b * 4096 + bx * 256) * 128;
#pragma unroll
        for (int j = 0; j < 4; ++j) {
            const bf16* cp = rbT + (size_t)(wn * 64 + j * 16 + lm) * 128;
            rhv2[j] = *(const bf16x2*)(cp + by * 4 + wm * 2);
#pragma unroll
            for (int ii = 0; ii < 4; ++ii)
                rwv[j][ii] = *(const bf16x4*)(cp + 64 + ii * 16 + kq * 4);
        }
    }
    if (tid < 256) rs[tid] = 0.f;
    __syncthreads();
    // exp + per-lane row partials
    float ps[8][4];
#pragma unroll
    for (int i = 0; i < 8; ++i)
#pragma unroll
        for (int r = 0; r < 4; ++r) {
            float s = 0.f;
#pragma unroll
            for (int j = 0; j < 4; ++j) {
                float sv = acc[i][j][r] + (float)rhv2[j][i >> 2]
                                        + (float)rwv[j][i & 3][r];
                float e = __expf(sv - 8.f);
                acc[i][j][r] = e;
                s += e;
            }
            ps[i][r] = s;
        }
#pragma unroll
    for (int msk = 1; msk < 16; msk <<= 1)
#pragma unroll
        for (int i = 0; i < 8; ++i)
#pragma unroll
            for (int r = 0; r < 4; ++r)
                ps[i][r] += __shfl_xor(ps[i][r], msk);
    if (lm == 0) {
#pragma unroll
        for (int i = 0; i < 8; ++i)
#pragma unroll
            for (int r = 0; r < 4; ++r)
                atomicAdd(&rs[wm * 128 + i * 16 + kq * 4 + r], ps[i][r]);
    }
    // store exp(S) tile (direct fragment stores; r11 proved LDS-staging -7%)
    bf16* Pb = P + ((size_t)bz * 4096 + by * 256) * 4096 + bx * 256;
#pragma unroll
    for (int i = 0; i < 8; ++i)
#pragma unroll
        for (int j = 0; j < 4; ++j)
#pragma unroll
            for (int r = 0; r < 4; ++r)
                Pb[(size_t)(wm * 128 + i * 16 + kq * 4 + r) * 4096
                   + wn * 64 + j * 16 + lm] = (bf16)acc[i][j][r];
    __syncthreads();
    if (tid < 256)
        atomicAdd(&lsum[(size_t)bz * 4096 + by * 256 + tid], rs[tid]);
}

// split-K=4 PV on the 256^2 core: all 256 cols per block.
__global__ __launch_bounds__(512, 1) void gemm4b_kernel(
    const bf16* __restrict__ P, const bf16* __restrict__ v_cm,
    bf16* __restrict__ pacc, int gbase)
{
    __shared__ bf16 smem[65536];
    int flat = blockIdx.x + 16 * blockIdx.y + 64 * blockIdx.z;
    flat = (flat & 7) * 32 + (flat >> 3);
    const int by = flat & 15, kc = (flat >> 4) & 3, bz = flat >> 6;
    const int b = gbase + bz;
    const bf16* A = P + ((size_t)bz * 4096 + by * 256) * 4096 + kc * 1024;
    const bf16* Bm = v_cm + (size_t)b * 256 * 4096 + kc * 1024;
    f32x4 acc[8][4];
    gemm_core_256(A, 4096, Bm, 4096, 1024, acc, smem, smem + 32768);
    const int tid = threadIdx.x, lane = tid & 63, wid = tid >> 6;
    const int wm = wid >> 2, wn = wid & 3, lm = lane & 15, kq = lane >> 4;
    bf16* ob = pacc + ((size_t)kc * 16384 + bz * 4096 + by * 256) * 256;
#pragma unroll
    for (int i = 0; i < 8; ++i)
#pragma unroll
        for (int r = 0; r < 4; ++r)
#pragma unroll
            for (int j = 0; j < 4; ++j)
                ob[(size_t)(wm * 128 + i * 16 + kq * 4 + r) * 256
                   + wn * 64 + j * 16 + lm] = (bf16)acc[i][j][r];
}

// out_t[(gbase*4096)+row][c] = (sum_kc pacc[kc][row][c]) / lsum[row]
__global__ __launch_bounds__(256) void reduce4_kernel(
    const bf16* __restrict__ pacc, const float* __restrict__ lsum,
    bf16* __restrict__ out_t, int gbase)
{
    int t = blockIdx.x * 256 + threadIdx.x;   // 524288 threads
    int row = t >> 5;                          // 0..16383
    int c0 = (t & 31) * 8;
    bf16x8 p0 = *(const bf16x8*)(pacc + (size_t)row * 256 + c0);
    bf16x8 p1 = *(const bf16x8*)(pacc + (size_t)(16384 + row) * 256 + c0);
    bf16x8 p2 = *(const bf16x8*)(pacc + (size_t)(32768 + row) * 256 + c0);
    bf16x8 p3 = *(const bf16x8*)(pacc + (size_t)(49152 + row) * 256 + c0);
    float inv = 1.f / lsum[row];
    bf16x8 o;
#pragma unroll
    for (int e = 0; e < 8; ++e)
        o[e] = (bf16)((((float)p0[e] + (float)p1[e]) +
                       ((float)p2[e] + (float)p3[e])) * inv);
    *(bf16x8*)(out_t + ((size_t)gbase * 4096 + row) * 256 + c0) = o;
}

// d_out[b][d][n] = x[b][d][n] + silu(bn2( sum_c w2b[d][c]*out_t[b*4096+n][c] ))
__global__ __launch_bounds__(512, 1) void gemm5_kernel(
    const bf16* __restrict__ w2b, const bf16* __restrict__ out_t,
    const float* __restrict__ bn2s, const float* __restrict__ bn2h,
    const float* __restrict__ x, float* __restrict__ out)
{
    __shared__ bf16 smem[65536];
    int b = blockIdx.z;
    const bf16* A = w2b + (size_t)(blockIdx.y * 256) * 256;              // d rows
    const bf16* Bm = out_t + ((size_t)b * 4096 + blockIdx.x * 256) * 256; // n rows
    f32x4 acc[8][4];
    gemm_core_256(A, 256, Bm, 256, 256, acc, smem, smem + 32768);
    const int tid = threadIdx.x, lane = tid & 63, wid = tid >> 6;
    const int wm = wid >> 2, wn = wid & 3, lm = lane & 15, kq = lane >> 4;
#pragma unroll
    for (int i = 0; i < 8; ++i)
#pragma unroll
        for (int j = 0; j < 4; ++j)
#pragma unroll
            for (int r = 0; r < 4; ++r) {
                int d = blockIdx.y * 256 + wm * 128 + i * 16 + kq * 4 + r;
                int n = blockIdx.x * 256 + wn * 64 + j * 16 + lm;
                float h = bn2s[d] * acc[i][j][r] + bn2h[d];
                size_t gi = ((size_t)(b * 512 + d)) * 4096 + n;
                out[gi] = x[gi] + silu_f(h);
            }
}

// ------------------------------- launcher ----------------------------------

extern "C" void kernel_launch(void* const* d_in, const int* in_sizes, int n_in,
                              void* d_out, int out_size, void* d_ws, size_t ws_size,
                              hipStream_t stream)
{
    (void)in_sizes; (void)n_in; (void)out_size; (void)ws_size;
    const float* x     = (const float*)d_in[0];
    const float* cv1_w = (const float*)d_in[1];
    const float* bn1_g = (const float*)d_in[2];
    const float* bn1_b = (const float*)d_in[3];
    const float* bn1_m = (const float*)d_in[4];
    const float* bn1_v = (const float*)d_in[5];
    const float* q_w   = (const float*)d_in[6];
    const float* q_b   = (const float*)d_in[7];
    const float* k_w   = (const float*)d_in[8];
    const float* k_b   = (const float*)d_in[9];
    const float* v_w   = (const float*)d_in[10];
    const float* v_b   = (const float*)d_in[11];
    const float* e_w   = (const float*)d_in[12];
    const float* e_b   = (const float*)d_in[13];
    const float* rel_h = (const float*)d_in[14];
    const float* rel_w = (const float*)d_in[15];
    const float* cv2_w = (const float*)d_in[16];
    const float* bn2_g = (const float*)d_in[17];
    const float* bn2_b = (const float*)d_in[18];
    const float* bn2_m = (const float*)d_in[19];
    const float* bn2_v = (const float*)d_in[20];
    float* out = (float*)d_out;

    char* ws = (char*)d_ws;
    bf16* P     = (bf16*)(ws + 0);            // 128 MB [4][4096][4096]
    bf16* xt    = (bf16*)(ws + 0);            //  32 MB overlay
    bf16* x1t   = (bf16*)(ws + 33554432);     //  16 MB overlay
    bf16* v_nm  = (bf16*)(ws + 50331648);     //  16 MB overlay
    bf16* e_nm  = (bf16*)(ws + 67108864);     //  16 MB overlay
    bf16* qk    = (bf16*)(ws + 134217728);    //  32 MB [32768][512] (q|k)
    bf16* v_cm  = (bf16*)(ws + 167772160);    //  16 MB [8][256][4096]
    bf16* rhwT  = (bf16*)(ws + 184549376);    //   8 MB [8][4096][128]
    bf16* out_t = (bf16*)(ws + 192937984);    //  16 MB [32768][256]
    bf16* w1b   = (bf16*)(ws + 209715200);    // 256 KB
    bf16* wqkve = (bf16*)(ws + 209977344);    // 512 KB
    bf16* w2b   = (bf16*)(ws + 210501632);    // 256 KB
    bf16* posT  = (bf16*)(ws + 210763776);    //  64 KB [128][256]
    float* biasq= (float*)(ws + 210829312);   //   4 KB
    float* bn1s = (float*)(ws + 210833408);
    float* bn1h = (float*)(ws + 210834432);
    float* bn2s = (float*)(ws + 210835456);
    float* bn2h = (float*)(ws + 210837504);
    float* lsum = (float*)(ws + 210839552);   // 128 KB [2][4][4096] fp32
    // pacc (32 MB, [4][16384][256] bf16) lives in d_out: dead after reduce4,
    // and gemm5 (the only writer of d_out) runs strictly after.
    bf16* pacc  = (bf16*)d_out;

    prep_misc_kernel<<<2183, 256, 0, stream>>>(
        cv1_w, q_w, q_b, k_w, k_b, v_w, v_b, e_w, e_b, cv2_w,
        bn1_g, bn1_b, bn1_m, bn1_v, bn2_g, bn2_b, bn2_m, bn2_v,
        rel_h, rel_w,
        w1b, wqkve, w2b, posT, biasq, bn1s, bn1h, bn2s, bn2h);
    zero_lsum_kernel<<<128, 256, 0, stream>>>(lsum);
    transpose_x_kernel<<<dim3(64, 8, 8), 256, 0, stream>>>(x, xt);
    gemm1_kernel<<<dim3(2, 256), 256, 0, stream>>>(xt, w1b, bn1s, bn1h, x1t);
    gemm2_kernel<<<dim3(4, 128), 512, 0, stream>>>(x1t, wqkve, biasq, qk, v_nm, e_nm);
    gemm_rhw_kernel<<<dim3(32, 1, 8), 256, 0, stream>>>(posT, e_nm, rhwT);
    transpose_v_kernel<<<dim3(64, 4, 8), 256, 0, stream>>>(v_nm, v_cm);
    for (int g = 0; g < 2; ++g) {
        float* ls = lsum + (size_t)g * 4 * 4096;
        gemm3b_kernel<<<dim3(16, 16, 4), 512, 0, stream>>>(qk, rhwT, P, ls, g * 4);
        gemm4b_kernel<<<dim3(16, 4, 4), 512, 0, stream>>>(P, v_cm, pacc, g * 4);
        reduce4_kernel<<<2048, 256, 0, stream>>>(pacc, ls, out_t, g * 4);
    }
    gemm5_kernel<<<dim3(16, 2, 8), 512, 0, stream>>>(w2b, out_t, bn2s, bn2h, x, out);
}

// Round 9
// 506.912 us; speedup vs baseline: 1.0704x; 1.0704x over previous
//
#include <hip/hip_runtime.h>

// ---------------------------------------------------------------------------
// ExtraPositionPromptSABottleneck on MI355X (gfx950)
// B=8, DIMS=512, C=256, H=W=64, N=4096.
//
// Round 13:
//  - FUSED attention kernel (gemm3b + gemm4b + reduce4 -> attn_kernel):
//    no P round-trip (520 MB deleted).  Fixed exp(S-8) offset => no online
//    max, fusion is exact.  Per block (128 q-rows x one batch): 32 m-tiles,
//    each {K-chunk staged dbuf -> S^T MFMA -> +pos,exp,rowsum -> P to LDS
//    (swizzled, b64 writes) -> V-chunk staged dbuf -> PV MFMA into f32 acc}.
//    Counted vmcnt(2) throughout; 256-chunk pipeline per block (vs 4 before
//    -- r6/r7/r8/r12 all proved 4-iteration blocks are schedule-immune).
//    XCD swizzle: batch = block&7 -> each XCD L2 holds its batch K+V (4MB).
//  - rhw reverted to [b][r][m] orientation (m-contig for the fused kernel).
//  - gemm2/gemm5 back on the round-10 2-phase core (r12 phase-split was -7us).
// ---------------------------------------------------------------------------

typedef __bf16 bf16;
typedef __attribute__((ext_vector_type(8))) __bf16 bf16x8;
typedef __attribute__((ext_vector_type(4))) __bf16 bf16x4;
typedef __attribute__((ext_vector_type(4))) float f32x4;

__device__ __forceinline__ float silu_f(float x) { return x / (1.f + __expf(-x)); }

__device__ __forceinline__ void zero_acc(f32x4 (&acc)[4][4])
{
#pragma unroll
    for (int i = 0; i < 4; ++i)
#pragma unroll
        for (int j = 0; j < 4; ++j)
            acc[i][j] = (f32x4){0.f, 0.f, 0.f, 0.f};
}

__device__ __forceinline__ void load_lds16(const bf16* g, bf16* l)
{
    __builtin_amdgcn_global_load_lds(
        (const __attribute__((address_space(1))) unsigned int*)g,
        (__attribute__((address_space(3))) unsigned int*)l, 16, 0, 0);
}

__device__ __forceinline__ void wg_barrier()
{
    asm volatile("" ::: "memory");
    __builtin_amdgcn_s_barrier();
    asm volatile("" ::: "memory");
}

// ---- counted-vmcnt double-buffered GEMM core: 256 thr, tile 128x128, BK=32
// (used by gemm1, rhw)
__device__ __forceinline__ void gemm_core_db(
    const bf16* __restrict__ A, int lda,
    const bf16* __restrict__ B, int ldb,
    int K, f32x4 (&acc)[4][4])
{
    __shared__ bf16 As[2][128 * 32];
    __shared__ bf16 Bs[2][128 * 32];
    const int tid = threadIdx.x;
    const int wave = tid >> 6;
    const int lane = tid & 63;
    const int lm = lane & 15;
    const int kq = lane >> 4;
    const int m0 = (wave >> 1) * 64;
    const int n0 = (wave & 1) * 64;
    const int srow = tid >> 2;
    const int skoff = (((tid & 3) ^ ((tid >> 3) & 3))) * 8;
    const int krd = (kq ^ ((lm >> 1) & 3)) * 8;
    zero_acc(acc);
    const bf16* ga = A + (size_t)srow * lda + skoff;
    const bf16* gb = B + (size_t)srow * ldb + skoff;
    load_lds16(ga, As[0] + tid * 8);
    load_lds16(ga + (size_t)64 * lda, As[0] + tid * 8 + 64 * 32);
    load_lds16(gb, Bs[0] + tid * 8);
    load_lds16(gb + (size_t)64 * ldb, Bs[0] + tid * 8 + 64 * 32);
    const int nt = K >> 5;
    for (int t = 0; t < nt; ++t) {
        const int cur = t & 1;
        if (t + 1 < nt) {
            const bf16* na = ga + (t + 1) * 32;
            const bf16* nb = gb + (t + 1) * 32;
            bf16* dA = As[cur ^ 1] + tid * 8;
            bf16* dB = Bs[cur ^ 1] + tid * 8;
            load_lds16(na, dA);
            load_lds16(na + (size_t)64 * lda, dA + 64 * 32);
            load_lds16(nb, dB);
            load_lds16(nb + (size_t)64 * ldb, dB + 64 * 32);
            asm volatile("s_waitcnt vmcnt(4)" ::: "memory");
        } else {
            asm volatile("s_waitcnt vmcnt(0)" ::: "memory");
        }
        wg_barrier();
        const bf16* as = As[cur];
        const bf16* bs = Bs[cur];
        bf16x8 av[4], bv[4];
#pragma unroll
        for (int tt = 0; tt < 4; ++tt)
            av[tt] = *(const bf16x8*)(as + (m0 + tt * 16 + lm) * 32 + krd);
#pragma unroll
        for (int tt = 0; tt < 4; ++tt)
            bv[tt] = *(const bf16x8*)(bs + (n0 + tt * 16 + lm) * 32 + krd);
#pragma unroll
        for (int i = 0; i < 4; ++i)
#pragma unroll
            for (int j = 0; j < 4; ++j)
                acc[i][j] = __builtin_amdgcn_mfma_f32_16x16x32_bf16(
                    av[i], bv[j], acc[i][j], 0, 0, 0);
        wg_barrier();
    }
}

// ---- 256x256 / BK=64 / 512-thread (8-wave, 2m x 4n) GEMM core (round-10).
__device__ __forceinline__ void gemm_core_256(
    const bf16* __restrict__ A, int lda,
    const bf16* __restrict__ B, int ldb,
    int K, f32x4 (&acc)[8][4])
{
    __shared__ bf16 As[2][16384];
    __shared__ bf16 Bs[2][16384];
    const int tid = threadIdx.x;
    const int lane = tid & 63;
    const int wid = tid >> 6;
    const int wm = wid >> 2, wn = wid & 3;
    const int lm = lane & 15, kq = lane >> 4;
    const int srow = tid >> 3;
    const int skoff = ((tid & 7) ^ (srow & 7)) * 8;
    const bf16* ga = A + (size_t)srow * lda + skoff;
    const bf16* gb = B + (size_t)srow * ldb + skoff;
#pragma unroll
    for (int r = 0; r < 4; ++r)
        load_lds16(ga + (size_t)(64 * r) * lda, As[0] + tid * 8 + r * 4096);
#pragma unroll
    for (int r = 0; r < 4; ++r)
        load_lds16(gb + (size_t)(64 * r) * ldb, Bs[0] + tid * 8 + r * 4096);
#pragma unroll
    for (int i = 0; i < 8; ++i)
#pragma unroll
        for (int j = 0; j < 4; ++j)
            acc[i][j] = (f32x4){0.f, 0.f, 0.f, 0.f};
    const int nt = K >> 6;
    for (int t = 0; t < nt; ++t) {
        const int cur = t & 1;
        if (t + 1 < nt) {
            const bf16* na = ga + (t + 1) * 64;
            const bf16* nb = gb + (t + 1) * 64;
#pragma unroll
            for (int r = 0; r < 4; ++r)
                load_lds16(na + (size_t)(64 * r) * lda,
                           As[cur ^ 1] + tid * 8 + r * 4096);
#pragma unroll
            for (int r = 0; r < 4; ++r)
                load_lds16(nb + (size_t)(64 * r) * ldb,
                           Bs[cur ^ 1] + tid * 8 + r * 4096);
            asm volatile("s_waitcnt vmcnt(8)" ::: "memory");
        } else {
            asm volatile("s_waitcnt vmcnt(0)" ::: "memory");
        }
        wg_barrier();
        const bf16* as = As[cur];
        const bf16* bs = Bs[cur];
#pragma unroll
        for (int ks = 0; ks < 2; ++ks) {
            bf16x8 av[8], bv[4];
#pragma unroll
            for (int i = 0; i < 8; ++i) {
                int lr = wm * 128 + i * 16 + lm;
                av[i] = *(const bf16x8*)(as + lr * 64 +
                                         (((ks << 2) | kq) ^ (lr & 7)) * 8);
            }
#pragma unroll
            for (int j = 0; j < 4; ++j) {
                int lr = wn * 64 + j * 16 + lm;
                bv[j] = *(const bf16x8*)(bs + lr * 64 +
                                         (((ks << 2) | kq) ^ (lr & 7)) * 8);
            }
            __builtin_amdgcn_s_setprio(1);
#pragma unroll
            for (int i = 0; i < 8; ++i)
#pragma unroll
                for (int j = 0; j < 4; ++j)
                    acc[i][j] = __builtin_amdgcn_mfma_f32_16x16x32_bf16(
                        av[i], bv[j], acc[i][j], 0, 0, 0);
            __builtin_amdgcn_s_setprio(0);
        }
        wg_barrier();
    }
}

// ------------------------------ prep kernels -------------------------------

__global__ __launch_bounds__(256) void prep_misc_kernel(
    const float* __restrict__ cv1_w,
    const float* __restrict__ qw, const float* __restrict__ qb,
    const float* __restrict__ kw, const float* __restrict__ kb,
    const float* __restrict__ vw, const float* __restrict__ vb,
    const float* __restrict__ ew, const float* __restrict__ eb,
    const float* __restrict__ cv2_w,
    const float* __restrict__ g1, const float* __restrict__ b1,
    const float* __restrict__ m1, const float* __restrict__ v1,
    const float* __restrict__ g2, const float* __restrict__ b2,
    const float* __restrict__ m2, const float* __restrict__ v2,
    const float* __restrict__ rel_h, const float* __restrict__ rel_w,
    bf16* __restrict__ w1b, bf16* __restrict__ wqkve, bf16* __restrict__ w2b,
    bf16* __restrict__ posT,
    float* __restrict__ biasq,
    float* __restrict__ bn1s, float* __restrict__ bn1h,
    float* __restrict__ bn2s, float* __restrict__ bn2h)
{
    int idx = blockIdx.x * 256 + threadIdx.x;
    if (idx < 131072) { w1b[idx] = (bf16)cv1_w[idx]; return; }
    idx -= 131072;
    if (idx < 262144) {
        int j = idx >> 8, c = idx & 255;
        int p = j >> 8, r = j & 255;
        const float* w = (p == 0) ? qw : (p == 1) ? kw : (p == 2) ? vw : ew;
        wqkve[idx] = (bf16)w[r * 256 + c];
        return;
    }
    idx -= 262144;
    if (idx < 131072) { w2b[idx] = (bf16)cv2_w[idx]; return; }
    idx -= 131072;
    if (idx < 1024) {
        int p = idx >> 8, r = idx & 255;
        const float* bb = (p == 0) ? qb : (p == 1) ? kb : (p == 2) ? vb : eb;
        biasq[idx] = bb[r];
        return;
    }
    idx -= 1024;
    if (idx < 256) {
        float s = g1[idx] * rsqrtf(v1[idx] + 1e-5f);
        bn1s[idx] = s;
        bn1h[idx] = b1[idx] - m1[idx] * s;
        return;
    }
    idx -= 256;
    if (idx < 512) {
        float s = g2[idx] * rsqrtf(v2[idx] + 1e-5f);
        bn2s[idx] = s;
        bn2h[idx] = b2[idx] - m2[idx] * s;
        return;
    }
    idx -= 512;
    if (idx < 32768) {
        // posT[r][c], r<64: rel_h[c][r]; r>=64: rel_w[c][r-64]
        int r = idx >> 8, c = idx & 255;
        posT[idx] = (bf16)((r < 64) ? rel_h[c * 64 + r] : rel_w[c * 64 + (r - 64)]);
        return;
    }
}

// xt[b*4096+n][d] = (bf16) x[b][d][n]
__global__ __launch_bounds__(256) void transpose_x_kernel(
    const float* __restrict__ x, bf16* __restrict__ xt)
{
    __shared__ float tile[64][65];
    int b = blockIdx.z;
    int n0 = blockIdx.x * 64;
    int d0 = blockIdx.y * 64;
    int tx = threadIdx.x & 63, ty = threadIdx.x >> 6;
#pragma unroll
    for (int i = 0; i < 16; ++i) {
        int d = i * 4 + ty;
        tile[d][tx] = x[((size_t)(b * 512 + d0 + d)) * 4096 + n0 + tx];
    }
    __syncthreads();
#pragma unroll
    for (int i = 0; i < 16; ++i) {
        int n = i * 4 + ty;
        xt[((size_t)(b * 4096 + n0 + n)) * 512 + d0 + tx] = (bf16)tile[tx][n];
    }
}

// v_cm[b][c][m] = v_nm[b*4096+m][c]
__global__ __launch_bounds__(256) void transpose_v_kernel(
    const bf16* __restrict__ v_nm, bf16* __restrict__ v_cm)
{
    __shared__ float tile[64][65];
    int b = blockIdx.z;
    int m0 = blockIdx.x * 64;
    int c0 = blockIdx.y * 64;
    int tx = threadIdx.x & 63, ty = threadIdx.x >> 6;
#pragma unroll
    for (int i = 0; i < 16; ++i) {
        int m = i * 4 + ty;
        tile[m][tx] = (float)v_nm[((size_t)(b * 4096 + m0 + m)) * 256 + c0 + tx];
    }
    __syncthreads();
#pragma unroll
    for (int i = 0; i < 16; ++i) {
        int c = i * 4 + ty;
        v_cm[((size_t)(b * 256 + c0 + c)) * 4096 + m0 + tx] = (bf16)tile[tx][c];
    }
}

// ------------------------------ GEMM kernels -------------------------------

__global__ __launch_bounds__(256) void gemm1_kernel(
    const bf16* __restrict__ xt, const bf16* __restrict__ w1b,
    const float* __restrict__ bn1s, const float* __restrict__ bn1h,
    bf16* __restrict__ x1t)
{
    const bf16* A = xt + (size_t)(blockIdx.y * 128) * 512;
    const bf16* Bm = w1b + (size_t)(blockIdx.x * 128) * 512;
    f32x4 acc[4][4];
    gemm_core_db(A, 512, Bm, 512, 512, acc);
    int wave = threadIdx.x >> 6;
    int lane = threadIdx.x & 63;
    int m0 = blockIdx.y * 128 + (wave >> 1) * 64;
    int n0 = blockIdx.x * 128 + (wave & 1) * 64;
    int lm = lane & 15, kq = lane >> 4;
#pragma unroll
    for (int i = 0; i < 4; ++i)
#pragma unroll
        for (int j = 0; j < 4; ++j)
#pragma unroll
            for (int r = 0; r < 4; ++r) {
                int row = m0 + i * 16 + kq * 4 + r;
                int col = n0 + j * 16 + lm;
                float h = bn1s[col] * acc[i][j][r] + bn1h[col];
                x1t[(size_t)row * 256 + col] = (bf16)silu_f(h);
            }
}

// projections on the 256^2 core: bx=0,1 -> qk; bx=2 -> v_nm; bx=3 -> e_nm
__global__ __launch_bounds__(512, 1) void gemm2_kernel(
    const bf16* __restrict__ x1t, const bf16* __restrict__ wqkve,
    const float* __restrict__ biasq,
    bf16* __restrict__ qk, bf16* __restrict__ v_nm, bf16* __restrict__ e_nm)
{
    const int bx = blockIdx.x, by = blockIdx.y;
    const bf16* A = x1t + (size_t)(by * 256) * 256;
    const bf16* Bm = wqkve + (size_t)(bx * 256) * 256;
    f32x4 acc[8][4];
    gemm_core_256(A, 256, Bm, 256, 256, acc);
    const int tid = threadIdx.x, lane = tid & 63, wid = tid >> 6;
    const int wm = wid >> 2, wn = wid & 3, lm = lane & 15, kq = lane >> 4;
#pragma unroll
    for (int i = 0; i < 8; ++i)
#pragma unroll
        for (int j = 0; j < 4; ++j)
#pragma unroll
            for (int r = 0; r < 4; ++r) {
                int row = by * 256 + wm * 128 + i * 16 + kq * 4 + r;
                int col = bx * 256 + wn * 64 + j * 16 + lm;
                bf16 val = (bf16)(acc[i][j][r] + biasq[col]);
                if (bx < 2)          qk[(size_t)row * 512 + col] = val;
                else if (bx == 2)    v_nm[(size_t)row * 256 + (col - 512)] = val;
                else                 e_nm[(size_t)row * 256 + (col - 768)] = val;
            }
}

// rhw[b][r][m] = sum_c posT[r][c] * e_nm[b*4096+m][c]  (r<64: RH, r>=64: RW)
__global__ __launch_bounds__(256) void gemm_rhw_kernel(
    const bf16* __restrict__ posT, const bf16* __restrict__ e_nm,
    bf16* __restrict__ rhw)
{
    int b = blockIdx.z;
    const bf16* Bm = e_nm + ((size_t)b * 4096 + blockIdx.x * 128) * 256;
    f32x4 acc[4][4];
    gemm_core_db(posT, 256, Bm, 256, 256, acc);
    int wave = threadIdx.x >> 6;
    int lane = threadIdx.x & 63;
    int m0 = (wave >> 1) * 64, n0 = (wave & 1) * 64;
    int lm = lane & 15, kq = lane >> 4;
    bf16* rb = rhw + (size_t)b * 128 * 4096 + blockIdx.x * 128;
#pragma unroll
    for (int i = 0; i < 4; ++i)
#pragma unroll
        for (int j = 0; j < 4; ++j)
#pragma unroll
            for (int r = 0; r < 4; ++r)
                rb[(size_t)(m0 + i * 16 + kq * 4 + r) * 4096 + n0 + j * 16 + lm] =
                    (bf16)acc[i][j][r];
}

// ---------------------- fused attention (gemm3b+4b+reduce4) ----------------
// Per block: batch b, 128 q-rows.  out_t[row][c] = sum_m exp(S-8) v / rowsum.
// S^T orientation (A=K rows, B=Q rows) so exp(P) packs m-contiguous -> b64
// LDS writes.  K/V staged in a shared 2x16KB double buffer (time-disjoint).
__global__ __launch_bounds__(512, 1) void attn_kernel(
    const bf16* __restrict__ qk, const bf16* __restrict__ v_cm,
    const bf16* __restrict__ rhw, bf16* __restrict__ out_t)
{
    __shared__ bf16 Qs[32768];       // [128 q][256 ch], chunk ^= q&7
    __shared__ bf16 KV[2][8192];     // K: [128 m][64 ch] ^ m&7 | V: [256 c][32 m] ^ (c>>1)&3
    __shared__ bf16 Ps[16384];       // [128 q][128 m], chunk ^= q&7
    __shared__ float rs[128];
    const int flat = blockIdx.x;
    const int b = flat & 7, by = flat >> 3;     // XCD = batch -> K/V L2-resident
    const int tid = threadIdx.x;
    const int lane = tid & 63, wid = tid >> 6;
    const int lm = lane & 15, kq = lane >> 4;
    const int wmS = wid >> 2, wqS = wid & 3;    // S: m-half x q-quarter
    const int wqP = wid >> 2, wcP = wid & 3;    // PV: q-half x c-quarter
    if (tid < 128) rs[tid] = 0.f;

    const bf16* qbase = qk + ((size_t)(b * 4096 + by * 128)) * 512;
    const bf16* kbase = qk + (size_t)b * 4096 * 512 + 256;
    const bf16* vbase = v_cm + (size_t)b * 256 * 4096;
    const bf16* rhb   = rhw + (size_t)b * 128 * 4096;

    // stage Q once (64 KB, 8 rounds)
#pragma unroll
    for (int r = 0; r < 8; ++r) {
        int q = (tid >> 5) + r * 16;
        int cs = tid & 31;
        load_lds16(qbase + (size_t)q * 512 + ((cs ^ (q & 7)) << 3),
                   Qs + tid * 8 + r * 4096);
    }

    f32x4 acc_o[4][4];
#pragma unroll
    for (int i = 0; i < 4; ++i)
#pragma unroll
        for (int j = 0; j < 4; ++j)
            acc_o[i][j] = (f32x4){0.f, 0.f, 0.f, 0.f};
    float rsum_p[2] = {0.f, 0.f};

    auto stageK = [&](int mb, int ct, int buf) {
#pragma unroll
        for (int r = 0; r < 2; ++r) {
            int row = (tid >> 3) + r * 64;
            int cs = tid & 7;
            load_lds16(kbase + (size_t)(mb + row) * 512 + ct * 64
                           + ((cs ^ (row & 7)) << 3),
                       KV[buf] + tid * 8 + r * 4096);
        }
    };
    auto stageV = [&](int mb, int ms, int buf) {
#pragma unroll
        for (int r = 0; r < 2; ++r) {
            int row = (tid >> 2) + r * 128;
            int cs = tid & 3;
            load_lds16(vbase + (size_t)row * 4096 + mb + ms * 32
                           + ((cs ^ ((row >> 1) & 3)) << 3),
                       KV[buf] + tid * 8 + r * 4096);
        }
    };

#pragma unroll 1
    for (int mt = 0; mt < 32; ++mt) {
        const int mb = mt * 128;
        f32x4 acc_s[4][2];
#pragma unroll
        for (int i = 0; i < 4; ++i)
#pragma unroll
            for (int j = 0; j < 2; ++j)
                acc_s[i][j] = (f32x4){0.f, 0.f, 0.f, 0.f};

        auto compS = [&](int ct, int buf) {
            const bf16* ks = KV[buf];
#pragma unroll
            for (int k2 = 0; k2 < 2; ++k2) {
                bf16x8 av[4], bv[2];
#pragma unroll
                for (int i = 0; i < 4; ++i) {
                    int mr = wmS * 64 + i * 16 + lm;
                    av[i] = *(const bf16x8*)(ks + mr * 64 +
                                             (((k2 << 2) | kq) ^ (mr & 7)) * 8);
                }
#pragma unroll
                for (int j = 0; j < 2; ++j) {
                    int qr = wqS * 32 + j * 16 + lm;
                    bv[j] = *(const bf16x8*)(Qs + qr * 256 +
                        (((ct << 3) | (k2 << 2) | kq) ^ (qr & 7)) * 8);
                }
                __builtin_amdgcn_s_setprio(1);
#pragma unroll
                for (int i = 0; i < 4; ++i)
#pragma unroll
                    for (int j = 0; j < 2; ++j)
                        acc_s[i][j] = __builtin_amdgcn_mfma_f32_16x16x32_bf16(
                            av[i], bv[j], acc_s[i][j], 0, 0, 0);
                __builtin_amdgcn_s_setprio(0);
            }
        };
        auto compPV = [&](int ms, int buf) {
            const bf16* vs = KV[buf];
            bf16x8 pa[4], vv[4];
#pragma unroll
            for (int i = 0; i < 4; ++i) {
                int qr = wqP * 64 + i * 16 + lm;
                pa[i] = *(const bf16x8*)(Ps + qr * 128 +
                                         (((ms << 2) | kq) ^ (qr & 7)) * 8);
            }
#pragma unroll
            for (int j = 0; j < 4; ++j) {
                int cr = wcP * 64 + j * 16 + lm;
                vv[j] = *(const bf16x8*)(vs + cr * 32 +
                                         (kq ^ ((cr >> 1) & 3)) * 8);
            }
            __builtin_amdgcn_s_setprio(1);
#pragma unroll
            for (int i = 0; i < 4; ++i)
#pragma unroll
                for (int j = 0; j < 4; ++j)
                    acc_o[i][j] = __builtin_amdgcn_mfma_f32_16x16x32_bf16(
                        pa[i], vv[j], acc_o[i][j], 0, 0, 0);
            __builtin_amdgcn_s_setprio(0);
        };

        // ---- S phase: 4 ch-chunks, counted-vmcnt double buffer
        stageK(mb, 0, 0); stageK(mb, 1, 1);
        asm volatile("s_waitcnt vmcnt(2)" ::: "memory"); wg_barrier();
        compS(0, 0); wg_barrier();
        stageK(mb, 2, 0);
        asm volatile("s_waitcnt vmcnt(2)" ::: "memory"); wg_barrier();
        compS(1, 1); wg_barrier();
        stageK(mb, 3, 1);
        asm volatile("s_waitcnt vmcnt(2)" ::: "memory"); wg_barrier();
        // positional terms (L2-hot, m-contig x4); drained by the vmcnt(0)
        bf16x4 rh4[2][4], rw4[2][4];
#pragma unroll
        for (int j = 0; j < 2; ++j) {
            int hj = by * 2 + ((wqS * 32 + j * 16) >= 64 ? 1 : 0);
            int wj = (wqS * 32 + j * 16 + lm) & 63;
#pragma unroll
            for (int i = 0; i < 4; ++i) {
                int mo = mb + wmS * 64 + i * 16 + kq * 4;
                rh4[j][i] = *(const bf16x4*)(rhb + (size_t)hj * 4096 + mo);
                rw4[j][i] = *(const bf16x4*)(rhb + (size_t)(64 + wj) * 4096 + mo);
            }
        }
        compS(2, 0); wg_barrier();
        asm volatile("s_waitcnt vmcnt(0)" ::: "memory"); wg_barrier();
        compS(3, 1);
        // ---- exp + rowsum + P -> LDS (swizzled b64 writes)
#pragma unroll
        for (int i = 0; i < 4; ++i)
#pragma unroll
            for (int j = 0; j < 2; ++j) {
                bf16x4 pk;
#pragma unroll
                for (int r = 0; r < 4; ++r) {
                    float sv = acc_s[i][j][r] + (float)rh4[j][i][r]
                                              + (float)rw4[j][i][r];
                    float e = __expf(sv - 8.f);
                    rsum_p[j] += e;
                    pk[r] = (bf16)e;
                }
                int q = wqS * 32 + j * 16 + lm;
                int ck = wmS * 8 + i * 2 + (kq >> 1);
                *(bf16x4*)((char*)Ps + q * 256 + ((ck ^ (q & 7)) << 4)
                           + ((kq & 1) << 3)) = pk;
            }
        asm volatile("s_waitcnt lgkmcnt(0)" ::: "memory");
        wg_barrier();
        // ---- PV phase: 4 m-sub chunks of V
        stageV(mb, 0, 0); stageV(mb, 1, 1);
        asm volatile("s_waitcnt vmcnt(2)" ::: "memory"); wg_barrier();
        compPV(0, 0); wg_barrier();
        stageV(mb, 2, 0);
        asm volatile("s_waitcnt vmcnt(2)" ::: "memory"); wg_barrier();
        compPV(1, 1); wg_barrier();
        stageV(mb, 3, 1);
        asm volatile("s_waitcnt vmcnt(2)" ::: "memory"); wg_barrier();
        compPV(2, 0); wg_barrier();
        asm volatile("s_waitcnt vmcnt(0)" ::: "memory"); wg_barrier();
        compPV(3, 1); wg_barrier();
    }

    // ---- rowsums -> rs, then normalize + store
#pragma unroll
    for (int j = 0; j < 2; ++j) {
        rsum_p[j] += __shfl_xor(rsum_p[j], 16);
        rsum_p[j] += __shfl_xor(rsum_p[j], 32);
    }
    if (kq == 0) {
#pragma unroll
        for (int j = 0; j < 2; ++j)
            atomicAdd(&rs[wqS * 32 + j * 16 + lm], rsum_p[j]);
    }
    __syncthreads();
    bf16* ob = out_t + ((size_t)(b * 4096 + by * 128)) * 256;
#pragma unroll
    for (int i = 0; i < 4; ++i)
#pragma unroll
        for (int r = 0; r < 4; ++r) {
            int q = wqP * 64 + i * 16 + kq * 4 + r;
            float inv = 1.f / rs[q];
#pragma unroll
            for (int j = 0; j < 4; ++j)
                ob[(size_t)q * 256 + wcP * 64 + j * 16 + lm] =
                    (bf16)(acc_o[i][j][r] * inv);
        }
}

// d_out[b][d][n] = x[b][d][n] + silu(bn2( sum_c w2b[d][c]*out_t[b*4096+n][c] ))
__global__ __launch_bounds__(512, 1) void gemm5_kernel(
    const bf16* __restrict__ w2b, const bf16* __restrict__ out_t,
    const float* __restrict__ bn2s, const float* __restrict__ bn2h,
    const float* __restrict__ x, float* __restrict__ out)
{
    int b = blockIdx.z;
    const bf16* A = w2b + (size_t)(blockIdx.y * 256) * 256;
    const bf16* Bm = out_t + ((size_t)b * 4096 + blockIdx.x * 256) * 256;
    f32x4 acc[8][4];
    gemm_core_256(A, 256, Bm, 256, 256, acc);
    const int tid = threadIdx.x, lane = tid & 63, wid = tid >> 6;
    const int wm = wid >> 2, wn = wid & 3, lm = lane & 15, kq = lane >> 4;
#pragma unroll
    for (int i = 0; i < 8; ++i)
#pragma unroll
        for (int j = 0; j < 4; ++j)
#pragma unroll
            for (int r = 0; r < 4; ++r) {
                int d = blockIdx.y * 256 + wm * 128 + i * 16 + kq * 4 + r;
                int n = blockIdx.x * 256 + wn * 64 + j * 16 + lm;
                float h = bn2s[d] * acc[i][j][r] + bn2h[d];
                size_t gi = ((size_t)(b * 512 + d)) * 4096 + n;
                out[gi] = x[gi] + silu_f(h);
            }
}

// ------------------------------- launcher ----------------------------------

extern "C" void kernel_launch(void* const* d_in, const int* in_sizes, int n_in,
                              void* d_out, int out_size, void* d_ws, size_t ws_size,
                              hipStream_t stream)
{
    (void)in_sizes; (void)n_in; (void)out_size; (void)ws_size;
    const float* x     = (const float*)d_in[0];
    const float* cv1_w = (const float*)d_in[1];
    const float* bn1_g = (const float*)d_in[2];
    const float* bn1_b = (const float*)d_in[3];
    const float* bn1_m = (const float*)d_in[4];
    const float* bn1_v = (const float*)d_in[5];
    const float* q_w   = (const float*)d_in[6];
    const float* q_b   = (const float*)d_in[7];
    const float* k_w   = (const float*)d_in[8];
    const float* k_b   = (const float*)d_in[9];
    const float* v_w   = (const float*)d_in[10];
    const float* v_b   = (const float*)d_in[11];
    const float* e_w   = (const float*)d_in[12];
    const float* e_b   = (const float*)d_in[13];
    const float* rel_h = (const float*)d_in[14];
    const float* rel_w = (const float*)d_in[15];
    const float* cv2_w = (const float*)d_in[16];
    const float* bn2_g = (const float*)d_in[17];
    const float* bn2_b = (const float*)d_in[18];
    const float* bn2_m = (const float*)d_in[19];
    const float* bn2_v = (const float*)d_in[20];
    float* out = (float*)d_out;

    char* ws = (char*)d_ws;
    bf16* xt    = (bf16*)(ws + 0);            //  32 MB
    bf16* x1t   = (bf16*)(ws + 33554432);     //  16 MB
    bf16* v_nm  = (bf16*)(ws + 50331648);     //  16 MB
    bf16* e_nm  = (bf16*)(ws + 67108864);     //  16 MB
    bf16* qk    = (bf16*)(ws + 134217728);    //  32 MB [32768][512] (q|k)
    bf16* v_cm  = (bf16*)(ws + 167772160);    //  16 MB [8][256][4096]
    bf16* rhw   = (bf16*)(ws + 184549376);    //   8 MB [8][128][4096]
    bf16* out_t = (bf16*)(ws + 192937984);    //  16 MB [32768][256]
    bf16* w1b   = (bf16*)(ws + 209715200);    // 256 KB
    bf16* wqkve = (bf16*)(ws + 209977344);    // 512 KB
    bf16* w2b   = (bf16*)(ws + 210501632);    // 256 KB
    bf16* posT  = (bf16*)(ws + 210763776);    //  64 KB [128][256]
    float* biasq= (float*)(ws + 210829312);   //   4 KB
    float* bn1s = (float*)(ws + 210833408);
    float* bn1h = (float*)(ws + 210834432);
    float* bn2s = (float*)(ws + 210835456);
    float* bn2h = (float*)(ws + 210837504);

    prep_misc_kernel<<<2183, 256, 0, stream>>>(
        cv1_w, q_w, q_b, k_w, k_b, v_w, v_b, e_w, e_b, cv2_w,
        bn1_g, bn1_b, bn1_m, bn1_v, bn2_g, bn2_b, bn2_m, bn2_v,
        rel_h, rel_w,
        w1b, wqkve, w2b, posT, biasq, bn1s, bn1h, bn2s, bn2h);
    transpose_x_kernel<<<dim3(64, 8, 8), 256, 0, stream>>>(x, xt);
    gemm1_kernel<<<dim3(2, 256), 256, 0, stream>>>(xt, w1b, bn1s, bn1h, x1t);
    gemm2_kernel<<<dim3(4, 128), 512, 0, stream>>>(x1t, wqkve, biasq, qk, v_nm, e_nm);
    gemm_rhw_kernel<<<dim3(32, 1, 8), 256, 0, stream>>>(posT, e_nm, rhw);
    transpose_v_kernel<<<dim3(64, 4, 8), 256, 0, stream>>>(v_nm, v_cm);
    attn_kernel<<<256, 512, 0, stream>>>(qk, v_cm, rhw, out_t);
    gemm5_kernel<<<dim3(16, 2, 8), 512, 0, stream>>>(w2b, out_t, bn2s, bn2h, x, out);
}

// Round 10
// 469.959 us; speedup vs baseline: 1.1545x; 1.0786x over previous
//
#include <hip/hip_runtime.h>

// ---------------------------------------------------------------------------
// ExtraPositionPromptSABottleneck on MI355X (gfx950)
// B=8, DIMS=512, C=256, H=W=64, N=4096.
//
// Round 14 (attn_kernel rework; everything else = round 13):
//  - Q fragments held in REGISTERS (16 x bf16x8, loaded once from global):
//    Q is invariant over the 32 m-tiles; r13 re-read it from LDS every S
//    phase (1/3 of S-phase LDS traffic) -- deleted, and Qs (64KB) freed.
//  - 4-slot LDS ring (4 x 16KB) with issue-ahead-2 counted vmcnt: chunk g
//    issued 2 phases (~500cyc) before use vs r13's 1 phase (~250cyc) < L2
//    latency.  Per-phase waits audited: steady state [g,g+1,g+2] in flight,
//    vmcnt(4) drains exactly chunk g.  pos-loads drained by one vmcnt(0)/mt
//    at the Ps-write point (coincides with the lgkm barrier anyway).
//  - ONE barrier per phase (ring-reuse distance >= 2 phases makes the
//    second barrier redundant): ~10 barriers/mt vs ~18.
//  - LDS 131.5 -> 96.5KB; VGPR ~230 under __launch_bounds__(512,2).
// ---------------------------------------------------------------------------

typedef __bf16 bf16;
typedef __attribute__((ext_vector_type(8))) __bf16 bf16x8;
typedef __attribute__((ext_vector_type(4))) __bf16 bf16x4;
typedef __attribute__((ext_vector_type(4))) float f32x4;

__device__ __forceinline__ float silu_f(float x) { return x / (1.f + __expf(-x)); }

__device__ __forceinline__ void zero_acc(f32x4 (&acc)[4][4])
{
#pragma unroll
    for (int i = 0; i < 4; ++i)
#pragma unroll
        for (int j = 0; j < 4; ++j)
            acc[i][j] = (f32x4){0.f, 0.f, 0.f, 0.f};
}

__device__ __forceinline__ void load_lds16(const bf16* g, bf16* l)
{
    __builtin_amdgcn_global_load_lds(
        (const __attribute__((address_space(1))) unsigned int*)g,
        (__attribute__((address_space(3))) unsigned int*)l, 16, 0, 0);
}

__device__ __forceinline__ void wg_barrier()
{
    asm volatile("" ::: "memory");
    __builtin_amdgcn_s_barrier();
    asm volatile("" ::: "memory");
}

// ---- counted-vmcnt double-buffered GEMM core: 256 thr, tile 128x128, BK=32
// (used by gemm1, rhw)
__device__ __forceinline__ void gemm_core_db(
    const bf16* __restrict__ A, int lda,
    const bf16* __restrict__ B, int ldb,
    int K, f32x4 (&acc)[4][4])
{
    __shared__ bf16 As[2][128 * 32];
    __shared__ bf16 Bs[2][128 * 32];
    const int tid = threadIdx.x;
    const int wave = tid >> 6;
    const int lane = tid & 63;
    const int lm = lane & 15;
    const int kq = lane >> 4;
    const int m0 = (wave >> 1) * 64;
    const int n0 = (wave & 1) * 64;
    const int srow = tid >> 2;
    const int skoff = (((tid & 3) ^ ((tid >> 3) & 3))) * 8;
    const int krd = (kq ^ ((lm >> 1) & 3)) * 8;
    zero_acc(acc);
    const bf16* ga = A + (size_t)srow * lda + skoff;
    const bf16* gb = B + (size_t)srow * ldb + skoff;
    load_lds16(ga, As[0] + tid * 8);
    load_lds16(ga + (size_t)64 * lda, As[0] + tid * 8 + 64 * 32);
    load_lds16(gb, Bs[0] + tid * 8);
    load_lds16(gb + (size_t)64 * ldb, Bs[0] + tid * 8 + 64 * 32);
    const int nt = K >> 5;
    for (int t = 0; t < nt; ++t) {
        const int cur = t & 1;
        if (t + 1 < nt) {
            const bf16* na = ga + (t + 1) * 32;
            const bf16* nb = gb + (t + 1) * 32;
            bf16* dA = As[cur ^ 1] + tid * 8;
            bf16* dB = Bs[cur ^ 1] + tid * 8;
            load_lds16(na, dA);
            load_lds16(na + (size_t)64 * lda, dA + 64 * 32);
            load_lds16(nb, dB);
            load_lds16(nb + (size_t)64 * ldb, dB + 64 * 32);
            asm volatile("s_waitcnt vmcnt(4)" ::: "memory");
        } else {
            asm volatile("s_waitcnt vmcnt(0)" ::: "memory");
        }
        wg_barrier();
        const bf16* as = As[cur];
        const bf16* bs = Bs[cur];
        bf16x8 av[4], bv[4];
#pragma unroll
        for (int tt = 0; tt < 4; ++tt)
            av[tt] = *(const bf16x8*)(as + (m0 + tt * 16 + lm) * 32 + krd);
#pragma unroll
        for (int tt = 0; tt < 4; ++tt)
            bv[tt] = *(const bf16x8*)(bs + (n0 + tt * 16 + lm) * 32 + krd);
#pragma unroll
        for (int i = 0; i < 4; ++i)
#pragma unroll
            for (int j = 0; j < 4; ++j)
                acc[i][j] = __builtin_amdgcn_mfma_f32_16x16x32_bf16(
                    av[i], bv[j], acc[i][j], 0, 0, 0);
        wg_barrier();
    }
}

// ---- 256x256 / BK=64 / 512-thread (8-wave, 2m x 4n) GEMM core (round-10).
__device__ __forceinline__ void gemm_core_256(
    const bf16* __restrict__ A, int lda,
    const bf16* __restrict__ B, int ldb,
    int K, f32x4 (&acc)[8][4])
{
    __shared__ bf16 As[2][16384];
    __shared__ bf16 Bs[2][16384];
    const int tid = threadIdx.x;
    const int lane = tid & 63;
    const int wid = tid >> 6;
    const int wm = wid >> 2, wn = wid & 3;
    const int lm = lane & 15, kq = lane >> 4;
    const int srow = tid >> 3;
    const int skoff = ((tid & 7) ^ (srow & 7)) * 8;
    const bf16* ga = A + (size_t)srow * lda + skoff;
    const bf16* gb = B + (size_t)srow * ldb + skoff;
#pragma unroll
    for (int r = 0; r < 4; ++r)
        load_lds16(ga + (size_t)(64 * r) * lda, As[0] + tid * 8 + r * 4096);
#pragma unroll
    for (int r = 0; r < 4; ++r)
        load_lds16(gb + (size_t)(64 * r) * ldb, Bs[0] + tid * 8 + r * 4096);
#pragma unroll
    for (int i = 0; i < 8; ++i)
#pragma unroll
        for (int j = 0; j < 4; ++j)
            acc[i][j] = (f32x4){0.f, 0.f, 0.f, 0.f};
    const int nt = K >> 6;
    for (int t = 0; t < nt; ++t) {
        const int cur = t & 1;
        if (t + 1 < nt) {
            const bf16* na = ga + (t + 1) * 64;
            const bf16* nb = gb + (t + 1) * 64;
#pragma unroll
            for (int r = 0; r < 4; ++r)
                load_lds16(na + (size_t)(64 * r) * lda,
                           As[cur ^ 1] + tid * 8 + r * 4096);
#pragma unroll
            for (int r = 0; r < 4; ++r)
                load_lds16(nb + (size_t)(64 * r) * ldb,
                           Bs[cur ^ 1] + tid * 8 + r * 4096);
            asm volatile("s_waitcnt vmcnt(8)" ::: "memory");
        } else {
            asm volatile("s_waitcnt vmcnt(0)" ::: "memory");
        }
        wg_barrier();
        const bf16* as = As[cur];
        const bf16* bs = Bs[cur];
#pragma unroll
        for (int ks = 0; ks < 2; ++ks) {
            bf16x8 av[8], bv[4];
#pragma unroll
            for (int i = 0; i < 8; ++i) {
                int lr = wm * 128 + i * 16 + lm;
                av[i] = *(const bf16x8*)(as + lr * 64 +
                                         (((ks << 2) | kq) ^ (lr & 7)) * 8);
            }
#pragma unroll
            for (int j = 0; j < 4; ++j) {
                int lr = wn * 64 + j * 16 + lm;
                bv[j] = *(const bf16x8*)(bs + lr * 64 +
                                         (((ks << 2) | kq) ^ (lr & 7)) * 8);
            }
            __builtin_amdgcn_s_setprio(1);
#pragma unroll
            for (int i = 0; i < 8; ++i)
#pragma unroll
                for (int j = 0; j < 4; ++j)
                    acc[i][j] = __builtin_amdgcn_mfma_f32_16x16x32_bf16(
                        av[i], bv[j], acc[i][j], 0, 0, 0);
            __builtin_amdgcn_s_setprio(0);
        }
        wg_barrier();
    }
}

// ------------------------------ prep kernels -------------------------------

__global__ __launch_bounds__(256) void prep_misc_kernel(
    const float* __restrict__ cv1_w,
    const float* __restrict__ qw, const float* __restrict__ qb,
    const float* __restrict__ kw, const float* __restrict__ kb,
    const float* __restrict__ vw, const float* __restrict__ vb,
    const float* __restrict__ ew, const float* __restrict__ eb,
    const float* __restrict__ cv2_w,
    const float* __restrict__ g1, const float* __restrict__ b1,
    const float* __restrict__ m1, const float* __restrict__ v1,
    const float* __restrict__ g2, const float* __restrict__ b2,
    const float* __restrict__ m2, const float* __restrict__ v2,
    const float* __restrict__ rel_h, const float* __restrict__ rel_w,
    bf16* __restrict__ w1b, bf16* __restrict__ wqkve, bf16* __restrict__ w2b,
    bf16* __restrict__ posT,
    float* __restrict__ biasq,
    float* __restrict__ bn1s, float* __restrict__ bn1h,
    float* __restrict__ bn2s, float* __restrict__ bn2h)
{
    int idx = blockIdx.x * 256 + threadIdx.x;
    if (idx < 131072) { w1b[idx] = (bf16)cv1_w[idx]; return; }
    idx -= 131072;
    if (idx < 262144) {
        int j = idx >> 8, c = idx & 255;
        int p = j >> 8, r = j & 255;
        const float* w = (p == 0) ? qw : (p == 1) ? kw : (p == 2) ? vw : ew;
        wqkve[idx] = (bf16)w[r * 256 + c];
        return;
    }
    idx -= 262144;
    if (idx < 131072) { w2b[idx] = (bf16)cv2_w[idx]; return; }
    idx -= 131072;
    if (idx < 1024) {
        int p = idx >> 8, r = idx & 255;
        const float* bb = (p == 0) ? qb : (p == 1) ? kb : (p == 2) ? vb : eb;
        biasq[idx] = bb[r];
        return;
    }
    idx -= 1024;
    if (idx < 256) {
        float s = g1[idx] * rsqrtf(v1[idx] + 1e-5f);
        bn1s[idx] = s;
        bn1h[idx] = b1[idx] - m1[idx] * s;
        return;
    }
    idx -= 256;
    if (idx < 512) {
        float s = g2[idx] * rsqrtf(v2[idx] + 1e-5f);
        bn2s[idx] = s;
        bn2h[idx] = b2[idx] - m2[idx] * s;
        return;
    }
    idx -= 512;
    if (idx < 32768) {
        // posT[r][c], r<64: rel_h[c][r]; r>=64: rel_w[c][r-64]
        int r = idx >> 8, c = idx & 255;
        posT[idx] = (bf16)((r < 64) ? rel_h[c * 64 + r] : rel_w[c * 64 + (r - 64)]);
        return;
    }
}

// xt[b*4096+n][d] = (bf16) x[b][d][n]
__global__ __launch_bounds__(256) void transpose_x_kernel(
    const float* __restrict__ x, bf16* __restrict__ xt)
{
    __shared__ float tile[64][65];
    int b = blockIdx.z;
    int n0 = blockIdx.x * 64;
    int d0 = blockIdx.y * 64;
    int tx = threadIdx.x & 63, ty = threadIdx.x >> 6;
#pragma unroll
    for (int i = 0; i < 16; ++i) {
        int d = i * 4 + ty;
        tile[d][tx] = x[((size_t)(b * 512 + d0 + d)) * 4096 + n0 + tx];
    }
    __syncthreads();
#pragma unroll
    for (int i = 0; i < 16; ++i) {
        int n = i * 4 + ty;
        xt[((size_t)(b * 4096 + n0 + n)) * 512 + d0 + tx] = (bf16)tile[tx][n];
    }
}

// v_cm[b][c][m] = v_nm[b*4096+m][c]
__global__ __launch_bounds__(256) void transpose_v_kernel(
    const bf16* __restrict__ v_nm, bf16* __restrict__ v_cm)
{
    __shared__ float tile[64][65];
    int b = blockIdx.z;
    int m0 = blockIdx.x * 64;
    int c0 = blockIdx.y * 64;
    int tx = threadIdx.x & 63, ty = threadIdx.x >> 6;
#pragma unroll
    for (int i = 0; i < 16; ++i) {
        int m = i * 4 + ty;
        tile[m][tx] = (float)v_nm[((size_t)(b * 4096 + m0 + m)) * 256 + c0 + tx];
    }
    __syncthreads();
#pragma unroll
    for (int i = 0; i < 16; ++i) {
        int c = i * 4 + ty;
        v_cm[((size_t)(b * 256 + c0 + c)) * 4096 + m0 + tx] = (bf16)tile[tx][c];
    }
}

// ------------------------------ GEMM kernels ------------------------------

__global__ __launch_bounds__(256) void gemm1_kernel(
    const bf16* __restrict__ xt, const bf16* __restrict__ w1b,
    const float* __restrict__ bn1s, const float* __restrict__ bn1h,
    bf16* __restrict__ x1t)
{
    const bf16* A = xt + (size_t)(blockIdx.y * 128) * 512;
    const bf16* Bm = w1b + (size_t)(blockIdx.x * 128) * 512;
    f32x4 acc[4][4];
    gemm_core_db(A, 512, Bm, 512, 512, acc);
    int wave = threadIdx.x >> 6;
    int lane = threadIdx.x & 63;
    int m0 = blockIdx.y * 128 + (wave >> 1) * 64;
    int n0 = blockIdx.x * 128 + (wave & 1) * 64;
    int lm = lane & 15, kq = lane >> 4;
#pragma unroll
    for (int i = 0; i < 4; ++i)
#pragma unroll
        for (int j = 0; j < 4; ++j)
#pragma unroll
            for (int r = 0; r < 4; ++r) {
                int row = m0 + i * 16 + kq * 4 + r;
                int col = n0 + j * 16 + lm;
                float h = bn1s[col] * acc[i][j][r] + bn1h[col];
                x1t[(size_t)row * 256 + col] = (bf16)silu_f(h);
            }
}

// projections on the 256^2 core: bx=0,1 -> qk; bx=2 -> v_nm; bx=3 -> e_nm
__global__ __launch_bounds__(512, 1) void gemm2_kernel(
    const bf16* __restrict__ x1t, const bf16* __restrict__ wqkve,
    const float* __restrict__ biasq,
    bf16* __restrict__ qk, bf16* __restrict__ v_nm, bf16* __restrict__ e_nm)
{
    const int bx = blockIdx.x, by = blockIdx.y;
    const bf16* A = x1t + (size_t)(by * 256) * 256;
    const bf16* Bm = wqkve + (size_t)(bx * 256) * 256;
    f32x4 acc[8][4];
    gemm_core_256(A, 256, Bm, 256, 256, acc);
    const int tid = threadIdx.x, lane = tid & 63, wid = tid >> 6;
    const int wm = wid >> 2, wn = wid & 3, lm = lane & 15, kq = lane >> 4;
#pragma unroll
    for (int i = 0; i < 8; ++i)
#pragma unroll
        for (int j = 0; j < 4; ++j)
#pragma unroll
            for (int r = 0; r < 4; ++r) {
                int row = by * 256 + wm * 128 + i * 16 + kq * 4 + r;
                int col = bx * 256 + wn * 64 + j * 16 + lm;
                bf16 val = (bf16)(acc[i][j][r] + biasq[col]);
                if (bx < 2)          qk[(size_t)row * 512 + col] = val;
                else if (bx == 2)    v_nm[(size_t)row * 256 + (col - 512)] = val;
                else                 e_nm[(size_t)row * 256 + (col - 768)] = val;
            }
}

// rhw[b][r][m] = sum_c posT[r][c] * e_nm[b*4096+m][c]  (r<64: RH, r>=64: RW)
__global__ __launch_bounds__(256) void gemm_rhw_kernel(
    const bf16* __restrict__ posT, const bf16* __restrict__ e_nm,
    bf16* __restrict__ rhw)
{
    int b = blockIdx.z;
    const bf16* Bm = e_nm + ((size_t)b * 4096 + blockIdx.x * 128) * 256;
    f32x4 acc[4][4];
    gemm_core_db(posT, 256, Bm, 256, 256, acc);
    int wave = threadIdx.x >> 6;
    int lane = threadIdx.x & 63;
    int m0 = (wave >> 1) * 64, n0 = (wave & 1) * 64;
    int lm = lane & 15, kq = lane >> 4;
    bf16* rb = rhw + (size_t)b * 128 * 4096 + blockIdx.x * 128;
#pragma unroll
    for (int i = 0; i < 4; ++i)
#pragma unroll
        for (int j = 0; j < 4; ++j)
#pragma unroll
            for (int r = 0; r < 4; ++r)
                rb[(size_t)(m0 + i * 16 + kq * 4 + r) * 4096 + n0 + j * 16 + lm] =
                    (bf16)acc[i][j][r];
}

// ---------------------- fused attention (round-14 rework) ------------------
// Per block: batch b, 128 q-rows.  S^T orientation; Q fragments in registers;
// 4-slot 16KB LDS ring with issue-ahead-2 counted vmcnt; 1 barrier/phase.
__global__ __launch_bounds__(512, 2) void attn_kernel(
    const bf16* __restrict__ qk, const bf16* __restrict__ v_cm,
    const bf16* __restrict__ rhw, bf16* __restrict__ out_t)
{
    __shared__ bf16 RING[4][8192];   // K: [128 m][64 ch]^m&7 | V: [256 c][32 m]^(c>>1)&3
    __shared__ bf16 Ps[16384];       // [128 q][128 m], chunk ^= q&7
    __shared__ float rs[128];
    const int flat = blockIdx.x;
    const int b = flat & 7, by = flat >> 3;     // XCD = batch -> K/V L2-resident
    const int tid = threadIdx.x;
    const int lane = tid & 63, wid = tid >> 6;
    const int lm = lane & 15, kq = lane >> 4;
    const int wmS = wid >> 2, wqS = wid & 3;    // S: m-half x q-quarter
    const int wqP = wid >> 2, wcP = wid & 3;    // PV: q-half x c-quarter
    if (tid < 128) rs[tid] = 0.f;

    const bf16* qbase = qk + ((size_t)(b * 4096 + by * 128)) * 512;
    const bf16* kbase = qk + (size_t)b * 4096 * 512 + 256;
    const bf16* vbase = v_cm + (size_t)b * 256 * 4096;
    const bf16* rhb   = rhw + (size_t)b * 128 * 4096;

    // ---- Q fragments -> registers (loaded once; invariant over m-tiles)
    bf16x8 qreg[4][2][2];
#pragma unroll
    for (int ct = 0; ct < 4; ++ct)
#pragma unroll
        for (int k2 = 0; k2 < 2; ++k2)
#pragma unroll
            for (int j = 0; j < 2; ++j)
                qreg[ct][k2][j] = *(const bf16x8*)(
                    qbase + (size_t)(wqS * 32 + j * 16 + lm) * 512
                          + ct * 64 + k2 * 32 + kq * 8);

    f32x4 acc_o[4][4];
#pragma unroll
    for (int i = 0; i < 4; ++i)
#pragma unroll
        for (int j = 0; j < 4; ++j)
            acc_o[i][j] = (f32x4){0.f, 0.f, 0.f, 0.f};
    float rsum_p[2] = {0.f, 0.f};

    auto stageK = [&](int mb, int ct, bf16* dst) {
#pragma unroll
        for (int r = 0; r < 2; ++r) {
            int row = (tid >> 3) + r * 64;
            int cs = tid & 7;
            load_lds16(kbase + (size_t)(mb + row) * 512 + ct * 64
                           + ((cs ^ (row & 7)) << 3),
                       dst + tid * 8 + r * 4096);
        }
    };
    auto stageV = [&](int mb, int ms, bf16* dst) {
#pragma unroll
        for (int r = 0; r < 2; ++r) {
            int row = (tid >> 2) + r * 128;
            int cs = tid & 3;
            load_lds16(vbase + (size_t)row * 4096 + mb + ms * 32
                           + ((cs ^ ((row >> 1) & 3)) << 3),
                       dst + tid * 8 + r * 4096);
        }
    };

    // prologue: stage K0,K1 of tile 0
    stageK(0, 0, RING[0]);
    stageK(0, 1, RING[1]);

#pragma unroll 1
    for (int mt = 0; mt < 32; ++mt) {
        const int mb = mt * 128;
        f32x4 acc_s[4][2];
#pragma unroll
        for (int i = 0; i < 4; ++i)
#pragma unroll
            for (int j = 0; j < 2; ++j)
                acc_s[i][j] = (f32x4){0.f, 0.f, 0.f, 0.f};

        auto compS = [&](int ct, const bf16* ks) {
#pragma unroll
            for (int k2 = 0; k2 < 2; ++k2) {
                bf16x8 av[4];
#pragma unroll
                for (int i = 0; i < 4; ++i) {
                    int mr = wmS * 64 + i * 16 + lm;
                    av[i] = *(const bf16x8*)(ks + mr * 64 +
                                             (((k2 << 2) | kq) ^ (mr & 7)) * 8);
                }
                __builtin_amdgcn_s_setprio(1);
#pragma unroll
                for (int i = 0; i < 4; ++i)
#pragma unroll
                    for (int j = 0; j < 2; ++j)
                        acc_s[i][j] = __builtin_amdgcn_mfma_f32_16x16x32_bf16(
                            av[i], qreg[ct][k2][j], acc_s[i][j], 0, 0, 0);
                __builtin_amdgcn_s_setprio(0);
            }
        };
        auto compPV = [&](int ms, const bf16* vs) {
            bf16x8 pa[4], vv[4];
#pragma unroll
            for (int i = 0; i < 4; ++i) {
                int qr = wqP * 64 + i * 16 + lm;
                pa[i] = *(const bf16x8*)(Ps + qr * 128 +
                                         (((ms << 2) | kq) ^ (qr & 7)) * 8);
            }
#pragma unroll
            for (int j = 0; j < 4; ++j) {
                int cr = wcP * 64 + j * 16 + lm;
                vv[j] = *(const bf16x8*)(vs + cr * 32 +
                                         (kq ^ ((cr >> 1) & 3)) * 8);
            }
            __builtin_amdgcn_s_setprio(1);
#pragma unroll
            for (int i = 0; i < 4; ++i)
#pragma unroll
                for (int j = 0; j < 4; ++j)
                    acc_o[i][j] = __builtin_amdgcn_mfma_f32_16x16x32_bf16(
                        pa[i], vv[j], acc_o[i][j], 0, 0, 0);
            __builtin_amdgcn_s_setprio(0);
        };

        // p0: [in flight K0,K1] issue K2; wait K0
        stageK(mb, 2, RING[2]);
        asm volatile("s_waitcnt vmcnt(4)" ::: "memory");
        wg_barrier();
        compS(0, RING[0]);
        // p1: issue K3; wait K1
        stageK(mb, 3, RING[3]);
        asm volatile("s_waitcnt vmcnt(4)" ::: "memory");
        wg_barrier();
        compS(1, RING[1]);
        // p2: issue V0 (ring0: K0 reads done at p0, all waves past bar p1)
        stageV(mb, 0, RING[0]);
        asm volatile("s_waitcnt vmcnt(4)" ::: "memory");
        wg_barrier();
        compS(2, RING[2]);
        // p3: issue V1; wait K3
        stageV(mb, 1, RING[1]);
        asm volatile("s_waitcnt vmcnt(4)" ::: "memory");
        wg_barrier();
        compS(3, RING[3]);
        // ---- pos terms (L2-hot), drained with V0,V1 by one vmcnt(0)
        bf16x4 rh4[2][4], rw4[2][4];
#pragma unroll
        for (int j = 0; j < 2; ++j) {
            int hj = by * 2 + ((wqS * 32 + j * 16) >= 64 ? 1 : 0);
            int wj = (wqS * 32 + j * 16 + lm) & 63;
#pragma unroll
            for (int i = 0; i < 4; ++i) {
                int mo = mb + wmS * 64 + i * 16 + kq * 4;
                rh4[j][i] = *(const bf16x4*)(rhb + (size_t)hj * 4096 + mo);
                rw4[j][i] = *(const bf16x4*)(rhb + (size_t)(64 + wj) * 4096 + mo);
            }
        }
        asm volatile("s_waitcnt vmcnt(0)" ::: "memory");
        // exp + rowsum + P -> LDS (swizzled b64 writes)
#pragma unroll
        for (int i = 0; i < 4; ++i)
#pragma unroll
            for (int j = 0; j < 2; ++j) {
                bf16x4 pk;
#pragma unroll
                for (int r = 0; r < 4; ++r) {
                    float sv = acc_s[i][j][r] + (float)rh4[j][i][r]
                                              + (float)rw4[j][i][r];
                    float e = __expf(sv - 8.f);
                    rsum_p[j] += e;
                    pk[r] = (bf16)e;
                }
                int q = wqS * 32 + j * 16 + lm;
                int ck = wmS * 8 + i * 2 + (kq >> 1);
                *(bf16x4*)((char*)Ps + q * 256 + ((ck ^ (q & 7)) << 4)
                           + ((kq & 1) << 3)) = pk;
            }
        asm volatile("s_waitcnt lgkmcnt(0)" ::: "memory");
        // p4: issue V2 (ring2 free: K2 read at p2); V0 already drained
        stageV(mb, 2, RING[2]);
        wg_barrier();               // also publishes Ps to all waves
        compPV(0, RING[0]);
        // p5: issue V3
        stageV(mb, 3, RING[3]);
        wg_barrier();
        compPV(1, RING[1]);
        // p6: issue K0(mt+1); wait V2
        if (mt + 1 < 32) {
            stageK(mb + 128, 0, RING[0]);
            asm volatile("s_waitcnt vmcnt(4)" ::: "memory");
        } else {
            asm volatile("s_waitcnt vmcnt(2)" ::: "memory");
        }
        wg_barrier();
        compPV(2, RING[2]);
        // p7: issue K1(mt+1); wait V3
        if (mt + 1 < 32) {
            stageK(mb + 128, 1, RING[1]);
            asm volatile("s_waitcnt vmcnt(4)" ::: "memory");
        } else {
            asm volatile("s_waitcnt vmcnt(0)" ::: "memory");
        }
        wg_barrier();
        compPV(3, RING[3]);
    }

    // ---- rowsums -> rs, then normalize + store
#pragma unroll
    for (int j = 0; j < 2; ++j) {
        rsum_p[j] += __shfl_xor(rsum_p[j], 16);
        rsum_p[j] += __shfl_xor(rsum_p[j], 32);
    }
    if (kq == 0) {
#pragma unroll
        for (int j = 0; j < 2; ++j)
            atomicAdd(&rs[wqS * 32 + j * 16 + lm], rsum_p[j]);
    }
    __syncthreads();
    bf16* ob = out_t + ((size_t)(b * 4096 + by * 128)) * 256;
#pragma unroll
    for (int i = 0; i < 4; ++i)
#pragma unroll
        for (int r = 0; r < 4; ++r) {
            int q = wqP * 64 + i * 16 + kq * 4 + r;
            float inv = 1.f / rs[q];
#pragma unroll
            for (int j = 0; j < 4; ++j)
                ob[(size_t)q * 256 + wcP * 64 + j * 16 + lm] =
                    (bf16)(acc_o[i][j][r] * inv);
        }
}

// d_out[b][d][n] = x[b][d][n] + silu(bn2( sum_c w2b[d][c]*out_t[b*4096+n][c] ))
__global__ __launch_bounds__(512, 1) void gemm5_kernel(
    const bf16* __restrict__ w2b, const bf16* __restrict__ out_t,
    const float* __restrict__ bn2s, const float* __restrict__ bn2h,
    const float* __restrict__ x, float* __restrict__ out)
{
    int b = blockIdx.z;
    const bf16* A = w2b + (size_t)(blockIdx.y * 256) * 256;
    const bf16* Bm = out_t + ((size_t)b * 4096 + blockIdx.x * 256) * 256;
    f32x4 acc[8][4];
    gemm_core_256(A, 256, Bm, 256, 256, acc);
    const int tid = threadIdx.x, lane = tid & 63, wid = tid >> 6;
    const int wm = wid >> 2, wn = wid & 3, lm = lane & 15, kq = lane >> 4;
#pragma unroll
    for (int i = 0; i < 8; ++i)
#pragma unroll
        for (int j = 0; j < 4; ++j)
#pragma unroll
            for (int r = 0; r < 4; ++r) {
                int d = blockIdx.y * 256 + wm * 128 + i * 16 + kq * 4 + r;
                int n = blockIdx.x * 256 + wn * 64 + j * 16 + lm;
                float h = bn2s[d] * acc[i][j][r] + bn2h[d];
                size_t gi = ((size_t)(b * 512 + d)) * 4096 + n;
                out[gi] = x[gi] + silu_f(h);
            }
}

// ------------------------------- launcher ----------------------------------

extern "C" void kernel_launch(void* const* d_in, const int* in_sizes, int n_in,
                              void* d_out, int out_size, void* d_ws, size_t ws_size,
                              hipStream_t stream)
{
    (void)in_sizes; (void)n_in; (void)out_size; (void)ws_size;
    const float* x     = (const float*)d_in[0];
    const float* cv1_w = (const float*)d_in[1];
    const float* bn1_g = (const float*)d_in[2];
    const float* bn1_b = (const float*)d_in[3];
    const float* bn1_m = (const float*)d_in[4];
    const float* bn1_v = (const float*)d_in[5];
    const float* q_w   = (const float*)d_in[6];
    const float* q_b   = (const float*)d_in[7];
    const float* k_w   = (const float*)d_in[8];
    const float* k_b   = (const float*)d_in[9];
    const float* v_w   = (const float*)d_in[10];
    const float* v_b   = (const float*)d_in[11];
    const float* e_w   = (const float*)d_in[12];
    const float* e_b   = (const float*)d_in[13];
    const float* rel_h = (const float*)d_in[14];
    const float* rel_w = (const float*)d_in[15];
    const float* cv2_w = (const float*)d_in[16];
    const float* bn2_g = (const float*)d_in[17];
    const float* bn2_b = (const float*)d_in[18];
    const float* bn2_m = (const float*)d_in[19];
    const float* bn2_v = (const float*)d_in[20];
    float* out = (float*)d_out;

    char* ws = (char*)d_ws;
    bf16* xt    = (bf16*)(ws + 0);            //  32 MB
    bf16* x1t   = (bf16*)(ws + 33554432);     //  16 MB
    bf16* v_nm  = (bf16*)(ws + 50331648);     //  16 MB
    bf16* e_nm  = (bf16*)(ws + 67108864);     //  16 MB
    bf16* qk    = (bf16*)(ws + 134217728);    //  32 MB [32768][512] (q|k)
    bf16* v_cm  = (bf16*)(ws + 167772160);    //  16 MB [8][256][4096]
    bf16* rhw   = (bf16*)(ws + 184549376);    //   8 MB [8][128][4096]
    bf16* out_t = (bf16*)(ws + 192937984);    //  16 MB [32768][256]
    bf16* w1b   = (bf16*)(ws + 209715200);    // 256 KB
    bf16* wqkve = (bf16*)(ws + 209977344);    // 512 KB
    bf16* w2b   = (bf16*)(ws + 210501632);    // 256 KB
    bf16* posT  = (bf16*)(ws + 210763776);    //  64 KB [128][256]
    float* biasq= (float*)(ws + 210829312);   //   4 KB
    float* bn1s = (float*)(ws + 210833408);
    float* bn1h = (float*)(ws + 210834432);
    float* bn2s = (float*)(ws + 210835456);
    float* bn2h = (float*)(ws + 210837504);

    prep_misc_kernel<<<2183, 256, 0, stream>>>(
        cv1_w, q_w, q_b, k_w, k_b, v_w, v_b, e_w, e_b, cv2_w,
        bn1_g, bn1_b, bn1_m, bn1_v, bn2_g, bn2_b, bn2_m, bn2_v,
        rel_h, rel_w,
        w1b, wqkve, w2b, posT, biasq, bn1s, bn1h, bn2s, bn2h);
    transpose_x_kernel<<<dim3(64, 8, 8), 256, 0, stream>>>(x, xt);
    gemm1_kernel<<<dim3(2, 256), 256, 0, stream>>>(xt, w1b, bn1s, bn1h, x1t);
    gemm2_kernel<<<dim3(4, 128), 512, 0, stream>>>(x1t, wqkve, biasq, qk, v_nm, e_nm);
    gemm_rhw_kernel<<<dim3(32, 1, 8), 256, 0, stream>>>(posT, e_nm, rhw);
    transpose_v_kernel<<<dim3(64, 4, 8), 256, 0, stream>>>(v_nm, v_cm);
    attn_kernel<<<256, 512, 0, stream>>>(qk, v_cm, rhw, out_t);
    gemm5_kernel<<<dim3(16, 2, 8), 512, 0, stream>>>(w2b, out_t, bn2s, bn2h, x, out);
}